// Round 3
// baseline (277.943 us; speedup 1.0000x reference)
//
#include <hip/hip_runtime.h>
#include <hip/hip_bf16.h>

#define NLB 4096
#define NULB 6144
#define NROWS 16384   // 4096 + 2*6144
#define DD 128
#define NC 10
#define VW 12                // V row width: 10 probs + ones-col + pad
#define SEG 8
#define JSEG (NROWS / SEG)   // 2048
#define BI 256               // i-rows per block (4 waves x 64)
#define BJ 128               // j-rows per LDS tile

typedef __bf16 bf16_t;
typedef bf16_t bf16x8 __attribute__((ext_vector_type(8)));
typedef float f32x4 __attribute__((ext_vector_type(4)));
typedef unsigned int u32;

// ---------------- L2-normalize rows of [lb_feat; anchor; positive] -> bf16 F ----------------
__global__ void knorm(const float* __restrict__ lb, const float* __restrict__ an,
                      const float* __restrict__ po, bf16_t* __restrict__ F) {
  int row = blockIdx.x * 4 + (threadIdx.x >> 6);
  int lane = threadIdx.x & 63;
  const float* src;
  if (row < NLB) src = lb + (size_t)row * DD;
  else if (row < NLB + NULB) src = an + (size_t)(row - NLB) * DD;
  else src = po + (size_t)(row - NLB - NULB) * DD;
  float2 v = ((const float2*)src)[lane];
  float ss = v.x * v.x + v.y * v.y;
#pragma unroll
  for (int off = 32; off >= 1; off >>= 1) ss += __shfl_xor(ss, off);
  float inv = 1.0f / fmaxf(sqrtf(ss), 1e-12f);
  union { bf16_t h[2]; u32 u; } pk;
  pk.h[0] = (bf16_t)(v.x * inv);
  pk.h[1] = (bf16_t)(v.y * inv);
  ((u32*)F)[(size_t)row * (DD / 2) + lane] = pk.u;
}

// ---------------- build V rows (12-wide, ones at col 10) + class counts ----------------
__global__ void kprep(const float* __restrict__ onehot, const float* __restrict__ l1,
                      const float* __restrict__ l2, float* __restrict__ V,
                      float* __restrict__ cls) {
  __shared__ float lcnt[NC];
  int t = threadIdx.x;
  if (t < NC) lcnt[t] = 0.0f;
  __syncthreads();
  int gid = blockIdx.x * 256 + t;
  if (gid < NLB) {
    int idx = 0;
#pragma unroll
    for (int c = 0; c < NC; ++c) {
      float v = onehot[(size_t)gid * NC + c];
      V[(size_t)gid * VW + c] = v;
      if (v == 1.0f) idx = c;
    }
    V[(size_t)gid * VW + 10] = 1.0f;
    V[(size_t)gid * VW + 11] = 0.0f;
    atomicAdd(&lcnt[idx], 1.0f);
  } else {
    int r = gid - NLB;
    float a[NC], b[NC];
#pragma unroll
    for (int c = 0; c < NC; ++c) { a[c] = l1[(size_t)r * NC + c]; b[c] = l2[(size_t)r * NC + c]; }
    float m1 = a[0], m2 = b[0];
#pragma unroll
    for (int c = 1; c < NC; ++c) { m1 = fmaxf(m1, a[c]); m2 = fmaxf(m2, b[c]); }
    float s1 = 0.0f, s2 = 0.0f;
#pragma unroll
    for (int c = 0; c < NC; ++c) {
      s1 += expf(2.0f * (a[c] - m1));
      s2 += expf(2.0f * (b[c] - m2));
    }
    bool take1 = (s1 <= s2);  // max(prob1)=1/s1 >= 1/s2=max(prob2)
    float g[NC];
#pragma unroll
    for (int c = 0; c < NC; ++c) g[c] = take1 ? a[c] : b[c];
    float mg = g[0];
#pragma unroll
    for (int c = 1; c < NC; ++c) mg = fmaxf(mg, g[c]);
    float e[NC]; float sg = 0.0f;
#pragma unroll
    for (int c = 0; c < NC; ++c) { e[c] = expf(g[c] - mg); sg += e[c]; }
    float msk[NC];
#pragma unroll
    for (int c = 0; c < NC; ++c) msk[c] = ((e[c] / sg) >= 0.95f) ? g[c] : 0.0f;
    float mx = msk[0]; int mi = 0;
#pragma unroll
    for (int c = 1; c < NC; ++c) if (msk[c] > mx) { mx = msk[c]; mi = c; }
    if (mx != 0.0f) atomicAdd(&lcnt[mi], 2.0f);
    float mm = 2.0f * msk[0];
#pragma unroll
    for (int c = 1; c < NC; ++c) mm = fmaxf(mm, 2.0f * msk[c]);
    float p[NC]; float sp = 0.0f;
#pragma unroll
    for (int c = 0; c < NC; ++c) { p[c] = expf(2.0f * msk[c] - mm); sp += p[c]; }
#pragma unroll
    for (int c = 0; c < NC; ++c) {
      float pv = p[c] / sp;
      V[(size_t)(NLB + r) * VW + c] = pv;
      V[(size_t)(NLB + NULB + r) * VW + c] = pv;
    }
    V[(size_t)(NLB + r) * VW + 10] = 1.0f;
    V[(size_t)(NLB + r) * VW + 11] = 0.0f;
    V[(size_t)(NLB + NULB + r) * VW + 10] = 1.0f;
    V[(size_t)(NLB + NULB + r) * VW + 11] = 0.0f;
  }
  __syncthreads();
  if (t < NC) atomicAdd(&cls[t], lcnt[t]);
}

// ---------------- attention partials: exp(2*F F^T) @ [V|1] per j-segment ----------------
// 4 waves/block; each wave holds 64 stationary i-rows as 4 B-frag sets (64 VGPRs),
// streams j in 16-row A-frags from a swizzled 128-row LDS tile, shares each
// A-frag and each V-broadcast across the 4 i-sets (4x LDS amortization vs R2).
// acc[s][12]: cols 0..9 numerators, col 10 softmax denominator (ones column).
__launch_bounds__(256, 2)
__global__ void kattn(const bf16_t* __restrict__ F, const float* __restrict__ V,
                      float* __restrict__ P12) {
  __shared__ bf16_t Fs[BJ * 128];  // 32 KB, 16B-chunk XOR swizzle
  __shared__ float Vs[BJ * VW];    // 6 KB
  int t = threadIdx.x;
  int lane = t & 63;
  int wave = t >> 6;    // 0..3
  int q = lane >> 4;    // 0..3
  int r = lane & 15;    // 0..15
  int i0 = blockIdx.x * BI + wave * 64;
  int jbase = blockIdx.y * JSEG;

  // stationary B-frags: 4 i-sets x 16 rows
  bf16x8 bfr[4][4];
#pragma unroll
  for (int s = 0; s < 4; ++s)
#pragma unroll
    for (int kk = 0; kk < 4; ++kk)
      bfr[s][kk] = *(const bf16x8*)(F + (size_t)(i0 + s * 16 + r) * DD + kk * 32 + q * 8);

  f32x4 acc0[4], acc1[4], acc2[4];
#pragma unroll
  for (int s = 0; s < 4; ++s) {
    acc0[s] = (f32x4){0.f, 0.f, 0.f, 0.f};
    acc1[s] = (f32x4){0.f, 0.f, 0.f, 0.f};
    acc2[s] = (f32x4){0.f, 0.f, 0.f, 0.f};
  }

  for (int jt = 0; jt < JSEG; jt += BJ) {
    int j0 = jbase + jt;
    __syncthreads();
    // stage F tile: 2048 16B chunks, XOR-swizzled (phys chunk = col ^ (row&15))
#pragma unroll
    for (int it = 0; it < 8; ++it) {
      int cid = t + it * 256;          // 0..2047
      int row = cid >> 4;
      int col = cid & 15;
      uint4 dat = *(const uint4*)(F + (size_t)(j0 + row) * DD + col * 8);
      *(uint4*)&Fs[(row * 16 + (col ^ (row & 15))) * 8] = dat;
    }
    // stage V tile: 128 rows x 12 floats = 384 float4
#pragma unroll
    for (int it = 0; it < 2; ++it) {
      int idx = t + it * 256;
      if (idx < BJ * VW / 4)
        ((float4*)Vs)[idx] = ((const float4*)(V + (size_t)j0 * VW))[idx];
    }
    __syncthreads();

    for (int jj = 0; jj < BJ / 16; ++jj) {
      // A-frags for this 16-row j-chunk (shared across the 4 i-sets)
      bf16x8 afr[4];
      const bf16_t* fsrow = &Fs[(jj * 16 + r) * 128];
#pragma unroll
      for (int kk = 0; kk < 4; ++kk)
        afr[kk] = *(const bf16x8*)(fsrow + ((kk * 4 + q) ^ r) * 8);
      f32x4 cfr[4];
#pragma unroll
      for (int s = 0; s < 4; ++s) {
        cfr[s] = (f32x4){0.f, 0.f, 0.f, 0.f};
#pragma unroll
        for (int kk = 0; kk < 4; ++kk)
          cfr[s] = __builtin_amdgcn_mfma_f32_16x16x32_bf16(afr[kk], bfr[s][kk], cfr[s], 0, 0, 0);
      }
      // cfr[s][rg] = dot(F[j0+jj*16+q*4+rg], F[i0+s*16+r])
#pragma unroll
      for (int rg = 0; rg < 4; ++rg) {
        const float* vr = &Vs[(jj * 16 + q * 4 + rg) * VW];
        f32x4 v0 = *(const f32x4*)vr;
        f32x4 v1 = *(const f32x4*)(vr + 4);
        f32x4 v2 = *(const f32x4*)(vr + 8);
#pragma unroll
        for (int s = 0; s < 4; ++s) {
          float w = __builtin_amdgcn_exp2f(cfr[s][rg] * 2.8853900817779268f);  // exp(2*dot)
          acc0[s] += v0 * w;
          acc1[s] += v1 * w;
          acc2[s] += v2 * w;
        }
      }
    }
  }

  // reduce across quads (lanes sharing r hold disjoint j quarters)
#pragma unroll
  for (int off = 16; off <= 32; off <<= 1) {
#pragma unroll
    for (int s = 0; s < 4; ++s) {
#pragma unroll
      for (int k = 0; k < 4; ++k) {
        acc0[s][k] += __shfl_xor(acc0[s][k], off);
        acc1[s][k] += __shfl_xor(acc1[s][k], off);
      }
      acc2[s][0] += __shfl_xor(acc2[s][0], off);
      acc2[s][1] += __shfl_xor(acc2[s][1], off);
      acc2[s][2] += __shfl_xor(acc2[s][2], off);
    }
  }

  if (q == 0) {
#pragma unroll
    for (int s = 0; s < 4; ++s) {
      float* op = P12 + (size_t)(i0 + s * 16 + r) * VW;
      atomicAdd(&op[0], acc0[s][0]);
      atomicAdd(&op[1], acc0[s][1]);
      atomicAdd(&op[2], acc0[s][2]);
      atomicAdd(&op[3], acc0[s][3]);
      atomicAdd(&op[4], acc1[s][0]);
      atomicAdd(&op[5], acc1[s][1]);
      atomicAdd(&op[6], acc1[s][2]);
      atomicAdd(&op[7], acc1[s][3]);
      atomicAdd(&op[8], acc2[s][0]);
      atomicAdd(&op[9], acc2[s][1]);
      atomicAdd(&op[10], acc2[s][2]);
    }
  }
}

// ---------------- finalize: divide by softmax denom and class denom ----------------
__global__ void kfinal(float* __restrict__ out, const float* __restrict__ P12,
                       const float* __restrict__ cls) {
  int row = blockIdx.x * 256 + threadIdx.x;  // 64 blocks x 256
  float d[NC]; float tot = 0.0f;
#pragma unroll
  for (int c = 0; c < NC; ++c) { d[c] = cls[c]; tot += d[c]; }
  const float* pr = P12 + (size_t)row * VW;
  float rs = 1.0f / pr[10];
  float* op = out + (size_t)row * NC;
#pragma unroll
  for (int c = 0; c < NC; ++c) {
    float den = (d[c] == 0.0f) ? tot : d[c];
    op[c] = pr[c] * rs / den;
  }
}

extern "C" void kernel_launch(void* const* d_in, const int* in_sizes, int n_in,
                              void* d_out, int out_size, void* d_ws, size_t ws_size,
                              hipStream_t stream) {
  const float* anchor   = (const float*)d_in[0];  // 6144x128
  const float* positive = (const float*)d_in[1];  // 6144x128
  const float* lbfeat   = (const float*)d_in[2];  // 4096x128
  const float* onehot   = (const float*)d_in[3];  // 4096x10
  const float* l1       = (const float*)d_in[4];  // 6144x10
  const float* l2       = (const float*)d_in[5];  // 6144x10
  float* out = (float*)d_out;                     // 16384x10

  char* ws = (char*)d_ws;
  bf16_t* F   = (bf16_t*)ws;                               // 4 MiB
  float*  V   = (float*)(ws + 4194304);                    // 16384*12*4 = 768 KiB
  float*  P12 = (float*)(ws + 4194304 + 786432);           // 768 KiB
  float*  cls = (float*)(ws + 4194304 + 786432 + 786432);  // 64 B

  hipMemsetAsync(P12, 0, 786432 + 64, stream);  // P12 + cls
  knorm<<<NROWS / 4, 256, 0, stream>>>(lbfeat, anchor, positive, F);
  kprep<<<(NLB + NULB) / 256, 256, 0, stream>>>(onehot, l1, l2, V, cls);
  kattn<<<dim3(NROWS / BI, SEG), 256, 0, stream>>>(F, V, P12);
  kfinal<<<NROWS / 256, 256, 0, stream>>>(out, P12, cls);
}

// Round 4
// 189.153 us; speedup vs baseline: 1.4694x; 1.4694x over previous
//
#include <hip/hip_runtime.h>
#include <hip/hip_bf16.h>

#define NLB 4096
#define NULB 6144
#define NROWS 16384   // 4096 + 2*6144
#define DD 128
#define NC 10
#define VW 12                // P12 row width: 10 numerators + denom + pad
#define SEG 8
#define JSEG (NROWS / SEG)   // 2048
#define BI 256               // i-rows per block (4 waves x 64)
#define BJ 128               // j-rows per LDS tile

typedef __bf16 bf16_t;
typedef bf16_t bf16x8 __attribute__((ext_vector_type(8)));
typedef bf16_t bf16x4 __attribute__((ext_vector_type(4)));
typedef float f32x4 __attribute__((ext_vector_type(4)));
typedef unsigned int u32;

// ---------------- L2-normalize rows of [lb_feat; anchor; positive] -> bf16 F ----------------
__global__ void knorm(const float* __restrict__ lb, const float* __restrict__ an,
                      const float* __restrict__ po, bf16_t* __restrict__ F) {
  int row = blockIdx.x * 4 + (threadIdx.x >> 6);
  int lane = threadIdx.x & 63;
  const float* src;
  if (row < NLB) src = lb + (size_t)row * DD;
  else if (row < NLB + NULB) src = an + (size_t)(row - NLB) * DD;
  else src = po + (size_t)(row - NLB - NULB) * DD;
  float2 v = ((const float2*)src)[lane];
  float ss = v.x * v.x + v.y * v.y;
#pragma unroll
  for (int off = 32; off >= 1; off >>= 1) ss += __shfl_xor(ss, off);
  float inv = 1.0f / fmaxf(sqrtf(ss), 1e-12f);
  union { bf16_t h[2]; u32 u; } pk;
  pk.h[0] = (bf16_t)(v.x * inv);
  pk.h[1] = (bf16_t)(v.y * inv);
  ((u32*)F)[(size_t)row * (DD / 2) + lane] = pk.u;
}

// ---------------- build V B-frags (hi/lo bf16) + class counts ----------------
// VF layout: per j16-group g (0..1023), lane l (0..63), idx d (0..3):
//   VF[g*256 + l*4 + d] = V[j = g*16 + (l>>4)*4 + d][c = l&15]
// where V row = [p0..p9, 1, 0,0,0,0,0]. hi = bf16(v), lo = bf16(v - hi).
__global__ void kprep(const float* __restrict__ onehot, const float* __restrict__ l1,
                      const float* __restrict__ l2, bf16_t* __restrict__ VFhi,
                      bf16_t* __restrict__ VFlo, float* __restrict__ cls) {
  __shared__ float lcnt[NC];
  int t = threadIdx.x;
  if (t < NC) lcnt[t] = 0.0f;
  __syncthreads();
  int gid = blockIdx.x * 256 + t;
  float p[NC];
  if (gid < NLB) {
    int idx = 0;
#pragma unroll
    for (int c = 0; c < NC; ++c) {
      p[c] = onehot[(size_t)gid * NC + c];
      if (p[c] == 1.0f) idx = c;
    }
    atomicAdd(&lcnt[idx], 1.0f);
  } else {
    int r = gid - NLB;
    float a[NC], b[NC];
#pragma unroll
    for (int c = 0; c < NC; ++c) { a[c] = l1[(size_t)r * NC + c]; b[c] = l2[(size_t)r * NC + c]; }
    float m1 = a[0], m2 = b[0];
#pragma unroll
    for (int c = 1; c < NC; ++c) { m1 = fmaxf(m1, a[c]); m2 = fmaxf(m2, b[c]); }
    float s1 = 0.0f, s2 = 0.0f;
#pragma unroll
    for (int c = 0; c < NC; ++c) {
      s1 += expf(2.0f * (a[c] - m1));
      s2 += expf(2.0f * (b[c] - m2));
    }
    bool take1 = (s1 <= s2);  // max(prob1)=1/s1 >= 1/s2=max(prob2)
    float g[NC];
#pragma unroll
    for (int c = 0; c < NC; ++c) g[c] = take1 ? a[c] : b[c];
    float mg = g[0];
#pragma unroll
    for (int c = 1; c < NC; ++c) mg = fmaxf(mg, g[c]);
    float e[NC]; float sg = 0.0f;
#pragma unroll
    for (int c = 0; c < NC; ++c) { e[c] = expf(g[c] - mg); sg += e[c]; }
    float msk[NC];
#pragma unroll
    for (int c = 0; c < NC; ++c) msk[c] = ((e[c] / sg) >= 0.95f) ? g[c] : 0.0f;
    float mx = msk[0]; int mi = 0;
#pragma unroll
    for (int c = 1; c < NC; ++c) if (msk[c] > mx) { mx = msk[c]; mi = c; }
    if (mx != 0.0f) atomicAdd(&lcnt[mi], 2.0f);
    float mm = 2.0f * msk[0];
#pragma unroll
    for (int c = 1; c < NC; ++c) mm = fmaxf(mm, 2.0f * msk[c]);
    float q[NC]; float sp = 0.0f;
#pragma unroll
    for (int c = 0; c < NC; ++c) { q[c] = expf(2.0f * msk[c] - mm); sp += q[c]; }
#pragma unroll
    for (int c = 0; c < NC; ++c) p[c] = q[c] / sp;
  }
  // scatter this row (and its duplicate for unlabeled) into VF hi/lo frag layout
  int nrep = (gid < NLB) ? 1 : 2;
  int rows[2];
  rows[0] = gid;
  rows[1] = gid + NULB;  // duplicate block offset (valid only when gid >= NLB)
  for (int rep = 0; rep < nrep; ++rep) {
    int j = rows[rep];
    int g = j >> 4;
    int q4 = (j & 15) >> 2;
    int d = j & 3;
#pragma unroll
    for (int c = 0; c < 16; ++c) {
      float v = (c < NC) ? p[c] : (c == 10 ? 1.0f : 0.0f);
      bf16_t hi = (bf16_t)v;
      bf16_t lo = (bf16_t)(v - (float)hi);
      size_t base = (size_t)g * 256 + (q4 * 16 + c) * 4 + d;
      VFhi[base] = hi;
      VFlo[base] = lo;
    }
  }
  __syncthreads();
  if (t < NC) atomicAdd(&cls[t], lcnt[t]);
}

// ---------------- attention partials: exp(2*F F^T) @ [V|1] per j-segment ----------------
// 4 waves/block; each wave holds 64 stationary i-rows (4 B-frag sets, 64 VGPRs).
// QK via mfma_16x16x32_bf16 from swizzled LDS; P exits in C-layout
// (lane(q,r) reg rg -> P[j=q*4+rg][i=r]) which IS the A-operand layout of a
// K=32 MFMA restricted to k=q*8+{0..3} -> PV done by MFMA with zero-padded
// P-frags and pre-fragged V (hi+lo bf16 split). Denominator = ones column 10.
__launch_bounds__(256, 2)
__global__ void kattn(const bf16_t* __restrict__ F, const bf16_t* __restrict__ VFhi,
                      const bf16_t* __restrict__ VFlo, float* __restrict__ P12) {
  __shared__ bf16_t Fs[BJ * 128];    // 32 KB, 16B-chunk XOR swizzle
  __shared__ bf16_t Vsh[BJ / 16 * 256];  // 4 KB hi frags
  __shared__ bf16_t Vsl[BJ / 16 * 256];  // 4 KB lo frags
  int t = threadIdx.x;
  int lane = t & 63;
  int wave = t >> 6;    // 0..3
  int q = lane >> 4;    // 0..3
  int r = lane & 15;    // 0..15
  int i0 = blockIdx.x * BI + wave * 64;
  int jbase = blockIdx.y * JSEG;

  // stationary B-frags: 4 i-sets x 16 rows
  bf16x8 bfr[4][4];
#pragma unroll
  for (int s = 0; s < 4; ++s)
#pragma unroll
    for (int kk = 0; kk < 4; ++kk)
      bfr[s][kk] = *(const bf16x8*)(F + (size_t)(i0 + s * 16 + r) * DD + kk * 32 + q * 8);

  f32x4 acc[4];
#pragma unroll
  for (int s = 0; s < 4; ++s) acc[s] = (f32x4){0.f, 0.f, 0.f, 0.f};

  const float C = 2.8853900817779268f;  // 2*log2(e): exp(2x) = 2^(Cx)

  for (int jt = 0; jt < JSEG; jt += BJ) {
    int j0 = jbase + jt;
    __syncthreads();
    // stage F tile: 2048 16B chunks, XOR-swizzled (phys chunk = col ^ (row&15))
#pragma unroll
    for (int it = 0; it < 8; ++it) {
      int cid = t + it * 256;          // 0..2047
      int row = cid >> 4;
      int col = cid & 15;
      uint4 dat = *(const uint4*)(F + (size_t)(j0 + row) * DD + col * 8);
      *(uint4*)&Fs[(row * 16 + (col ^ (row & 15))) * 8] = dat;
    }
    // stage V frags: 8 groups x 512 B each for hi and lo (256+256 float4)
    {
      int g0 = j0 >> 4;
      ((float4*)Vsh)[t] = ((const float4*)(VFhi + (size_t)g0 * 256))[t];
      ((float4*)Vsl)[t] = ((const float4*)(VFlo + (size_t)g0 * 256))[t];
    }
    __syncthreads();

#pragma unroll
    for (int jj = 0; jj < BJ / 16; ++jj) {
      // A-frags for this 16-row j-chunk (shared across the 4 i-sets)
      bf16x8 afr[4];
      const bf16_t* fsrow = &Fs[(jj * 16 + r) * 128];
#pragma unroll
      for (int kk = 0; kk < 4; ++kk)
        afr[kk] = *(const bf16x8*)(fsrow + ((kk * 4 + q) ^ r) * 8);
      f32x4 cfr[4];
#pragma unroll
      for (int s = 0; s < 4; ++s) {
        cfr[s] = (f32x4){0.f, 0.f, 0.f, 0.f};
#pragma unroll
        for (int kk = 0; kk < 4; ++kk)
          cfr[s] = __builtin_amdgcn_mfma_f32_16x16x32_bf16(afr[kk], bfr[s][kk], cfr[s], 0, 0, 0);
      }
      // V B-frags for this j-chunk: B[k=q*8+d][n=r] = V[jj*16+q*4+d][r], d<4; 0 pad
      bf16x4 vh = *(const bf16x4*)&Vsh[jj * 256 + lane * 4];
      bf16x4 vl = *(const bf16x4*)&Vsl[jj * 256 + lane * 4];
      bf16_t z = (bf16_t)0.0f;
      bf16x8 bh = {vh[0], vh[1], vh[2], vh[3], z, z, z, z};
      bf16x8 bl = {vl[0], vl[1], vl[2], vl[3], z, z, z, z};
      // P-frags: w = exp(2*dot) in bf16 at idx 0..3, zero pad
#pragma unroll
      for (int s = 0; s < 4; ++s) {
        float w0 = __builtin_amdgcn_exp2f(cfr[s][0] * C);
        float w1 = __builtin_amdgcn_exp2f(cfr[s][1] * C);
        float w2 = __builtin_amdgcn_exp2f(cfr[s][2] * C);
        float w3 = __builtin_amdgcn_exp2f(cfr[s][3] * C);
        bf16x8 pf = {(bf16_t)w0, (bf16_t)w1, (bf16_t)w2, (bf16_t)w3, z, z, z, z};
        acc[s] = __builtin_amdgcn_mfma_f32_16x16x32_bf16(pf, bh, acc[s], 0, 0, 0);
        acc[s] = __builtin_amdgcn_mfma_f32_16x16x32_bf16(pf, bl, acc[s], 0, 0, 0);
      }
    }
  }

  // acc[s] lane(q,r) reg rg = out_partial[row = i0+s*16+q*4+rg][col = r]
  if (r < 11) {
#pragma unroll
    for (int s = 0; s < 4; ++s) {
      float* op = P12 + (size_t)(i0 + s * 16 + q * 4) * VW + r;
      atomicAdd(&op[0 * VW], acc[s][0]);
      atomicAdd(&op[1 * VW], acc[s][1]);
      atomicAdd(&op[2 * VW], acc[s][2]);
      atomicAdd(&op[3 * VW], acc[s][3]);
    }
  }
}

// ---------------- finalize: divide by softmax denom and class denom ----------------
__global__ void kfinal(float* __restrict__ out, const float* __restrict__ P12,
                       const float* __restrict__ cls) {
  int row = blockIdx.x * 256 + threadIdx.x;  // 64 blocks x 256
  float d[NC]; float tot = 0.0f;
#pragma unroll
  for (int c = 0; c < NC; ++c) { d[c] = cls[c]; tot += d[c]; }
  const float* pr = P12 + (size_t)row * VW;
  float rs = 1.0f / pr[10];
  float* op = out + (size_t)row * NC;
#pragma unroll
  for (int c = 0; c < NC; ++c) {
    float den = (d[c] == 0.0f) ? tot : d[c];
    op[c] = pr[c] * rs / den;
  }
}

extern "C" void kernel_launch(void* const* d_in, const int* in_sizes, int n_in,
                              void* d_out, int out_size, void* d_ws, size_t ws_size,
                              hipStream_t stream) {
  const float* anchor   = (const float*)d_in[0];  // 6144x128
  const float* positive = (const float*)d_in[1];  // 6144x128
  const float* lbfeat   = (const float*)d_in[2];  // 4096x128
  const float* onehot   = (const float*)d_in[3];  // 4096x10
  const float* l1       = (const float*)d_in[4];  // 6144x10
  const float* l2       = (const float*)d_in[5];  // 6144x10
  float* out = (float*)d_out;                     // 16384x10

  char* ws = (char*)d_ws;
  bf16_t* F    = (bf16_t*)ws;                      // 4 MiB
  bf16_t* VFhi = (bf16_t*)(ws + 4194304);          // 1024*256*2 = 512 KiB
  bf16_t* VFlo = (bf16_t*)(ws + 4194304 + 524288); // 512 KiB
  float*  P12  = (float*)(ws + 4194304 + 1048576); // 16384*12*4 = 768 KiB
  float*  cls  = (float*)(ws + 4194304 + 1048576 + 786432);  // 64 B

  hipMemsetAsync(P12, 0, 786432 + 64, stream);  // P12 + cls
  knorm<<<NROWS / 4, 256, 0, stream>>>(lbfeat, anchor, positive, F);
  kprep<<<(NLB + NULB) / 256, 256, 0, stream>>>(onehot, l1, l2, VFhi, VFlo, cls);
  kattn<<<dim3(NROWS / BI, SEG), 256, 0, stream>>>(F, VFhi, VFlo, P12);
  kfinal<<<NROWS / 256, 256, 0, stream>>>(out, P12, cls);
}